// Round 3
// baseline (3212.438 us; speedup 1.0000x reference)
//
#include <hip/hip_runtime.h>

typedef unsigned short ushort_t;

// Problem constants
constexpr int B_    = 2;
constexpr int S_    = 1024;
constexpr int D_    = 512;
constexpr int E_    = 8;
constexpr int HMOE_ = 4;
constexpr int HD_   = 128;
constexpr int HID_  = 2048;
constexpr int AH_   = 4;
constexpr int NTOK  = B_ * S_;          // 2048 tokens
constexpr int NSUB  = B_ * HMOE_ * S_;  // 8192 sub-tokens
constexpr int TT    = 8;                // tokens per FFN workgroup

#define DEVINL __device__ __forceinline__

// ---------------------------------------------------------------------------
// GEMM: C[M,N] = A[M,K] @ W[K,N] + bias  (+ optional fp32 residual R)
// All fp32. 64x64 tile, BK=16, 256 threads, 4x4 per thread.
// ---------------------------------------------------------------------------
template <bool ADD_R>
__global__ __launch_bounds__(256) void gemm_bias_k(
    const float* __restrict__ A, const float* __restrict__ W,
    const float* __restrict__ bias, const float* __restrict__ R,
    float* __restrict__ C, int M, int N, int Kd)
{
    __shared__ float As[16][68];   // +4 pad: keeps 16B alignment, kills store conflicts
    __shared__ float Bs[16][68];
    const int tid = threadIdx.x;
    const int tx = tid & 15, ty = tid >> 4;
    const int m0 = blockIdx.y * 64, n0 = blockIdx.x * 64;
    float acc[4][4] = {};
    for (int k0 = 0; k0 < Kd; k0 += 16) {
        #pragma unroll
        for (int j = 0; j < 4; j++) {
            int i = tid + 256 * j;
            int mm = i >> 4, kk = i & 15;
            As[kk][mm] = A[(size_t)(m0 + mm) * Kd + k0 + kk];
        }
        {
            int row = tid >> 4, col = (tid & 15) * 4;
            float4 bv = *reinterpret_cast<const float4*>(W + (size_t)(k0 + row) * N + n0 + col);
            *reinterpret_cast<float4*>(&Bs[row][col]) = bv;
        }
        __syncthreads();
        #pragma unroll
        for (int kk = 0; kk < 16; kk++) {
            float4 a = *reinterpret_cast<const float4*>(&As[kk][ty * 4]);
            float4 b = *reinterpret_cast<const float4*>(&Bs[kk][tx * 4]);
            float av[4] = {a.x, a.y, a.z, a.w};
            float bv[4] = {b.x, b.y, b.z, b.w};
            #pragma unroll
            for (int i = 0; i < 4; i++)
                #pragma unroll
                for (int j = 0; j < 4; j++)
                    acc[i][j] = fmaf(av[i], bv[j], acc[i][j]);
        }
        __syncthreads();
    }
    #pragma unroll
    for (int i = 0; i < 4; i++) {
        int m = m0 + ty * 4 + i;
        #pragma unroll
        for (int j = 0; j < 4; j++) {
            int n = n0 + tx * 4 + j;
            float v = acc[i][j] + bias[n];
            if (ADD_R) v += R[(size_t)m * N + n];
            C[(size_t)m * N + n] = v;
        }
    }
}

// ---------------------------------------------------------------------------
// LayerNorm over D=512, one 256-thread block per row. All fp32.
// ---------------------------------------------------------------------------
__global__ __launch_bounds__(256) void ln_k(
    const float* __restrict__ X, const float* __restrict__ w,
    const float* __restrict__ b, float* __restrict__ Y)
{
    __shared__ float red[8];
    const int row = blockIdx.x, tid = threadIdx.x;
    const float* x = X + (size_t)row * D_;
    float v0 = x[tid], v1 = x[tid + 256];
    float s = v0 + v1, ss = v0 * v0 + v1 * v1;
    #pragma unroll
    for (int off = 32; off; off >>= 1) {
        s  += __shfl_xor(s, off);
        ss += __shfl_xor(ss, off);
    }
    if ((tid & 63) == 0) { red[tid >> 6] = s; red[(tid >> 6) + 4] = ss; }
    __syncthreads();
    float mu  = (red[0] + red[1] + red[2] + red[3]) * (1.f / D_);
    float var = (red[4] + red[5] + red[6] + red[7]) * (1.f / D_) - mu * mu;
    float rs = rsqrtf(var + 1e-12f);
    Y[(size_t)row * D_ + tid]       = (v0 - mu) * rs * w[tid]       + b[tid];
    Y[(size_t)row * D_ + tid + 256] = (v1 - mu) * rs * w[tid + 256] + b[tid + 256];
}

// sub-token t = ((b*HMOE + h)*S + s)  ->  flat offset into [b,s,512] at col h*128
DEVINL size_t local_off(int t) {
    int bq = t >> 12, r = t & 4095, h = r >> 10, sI = r & 1023;
    return ((size_t)(bq * S_ + sI)) * D_ + (size_t)h * HD_;
}

// ---------------------------------------------------------------------------
// Gating: one wave per token. softmax over 8 experts, top-2 (lowest-index
// tie-break = lax.top_k), re-softmax of top-2 probs, atomic list append.
// ---------------------------------------------------------------------------
template <bool LOCAL>
__global__ __launch_bounds__(64) void gate_k(
    const float* __restrict__ X, const float* __restrict__ gw,
    const float* __restrict__ gb, int* __restrict__ counts,
    int* __restrict__ li, float* __restrict__ lwt, int cap)
{
    constexpr int DIMD = LOCAL ? HD_ : D_;
    constexpr int PL = DIMD / 64;
    const int t = blockIdx.x, lane = threadIdx.x;
    const float* x = X + (LOCAL ? local_off(t) : (size_t)t * D_);
    float xr[PL];
    #pragma unroll
    for (int i = 0; i < PL; i++) xr[i] = x[lane + 64 * i];
    float sc[8];
    #pragma unroll
    for (int e = 0; e < 8; e++) {
        float a = 0.f;
        #pragma unroll
        for (int i = 0; i < PL; i++)
            a = fmaf(xr[i], gw[(size_t)(lane + 64 * i) * E_ + e], a);
        #pragma unroll
        for (int o2 = 32; o2; o2 >>= 1) a += __shfl_xor(a, o2);
        sc[e] = a;
    }
    if (lane == 0) {
        float mx = -1e30f;
        #pragma unroll
        for (int e = 0; e < 8; e++) { sc[e] += gb[e]; mx = fmaxf(mx, sc[e]); }
        float p[8], psum = 0.f;
        #pragma unroll
        for (int e = 0; e < 8; e++) { p[e] = expf(sc[e] - mx); psum += p[e]; }
        float inv = 1.f / psum;
        #pragma unroll
        for (int e = 0; e < 8; e++) p[e] *= inv;
        int i0 = 0;
        for (int e = 1; e < 8; e++) if (p[e] > p[i0]) i0 = e;
        int i1 = (i0 == 0) ? 1 : 0;
        for (int e = 0; e < 8; e++) if (e != i0 && p[e] > p[i1]) i1 = e;
        float e0 = expf(p[i0]), e1 = expf(p[i1]);
        float wnorm = 1.f / (e0 + e1);
        int pos0 = atomicAdd(&counts[i0], 1);
        li[(size_t)i0 * cap + pos0] = t; lwt[(size_t)i0 * cap + pos0] = e0 * wnorm;
        int pos1 = atomicAdd(&counts[i1], 1);
        li[(size_t)i1 * cap + pos1] = t; lwt[(size_t)i1 * cap + pos1] = e1 * wnorm;
    }
}

// ---------------------------------------------------------------------------
// Grouped expert FFN: out[t] += w_t * (relu(x_t @ w1[e] + b1[e]) @ w2[e] + b2[e])
// One workgroup = (expert e, tile of TT=8 tokens). HID in chunks of 512 via LDS.
// DIMD = 128 (local MoE) or 512 (global MoE). atomicAdd scatter.
// ---------------------------------------------------------------------------
template <int DIMD>
__global__ __launch_bounds__(256) void ffn_k(
    const float* __restrict__ X,
    const float* __restrict__ w1, const float* __restrict__ b1,
    const float* __restrict__ w2, const float* __restrict__ b2,
    const int* __restrict__ counts, const int* __restrict__ li,
    const float* __restrict__ lwt, float* __restrict__ OUT,
    int maxblk, int cap)
{
    constexpr int HC = 512;  // h-chunk
    __shared__ float xs[TT][DIMD];
    __shared__ float hs[TT][HC];
    __shared__ int    tok[TT];
    __shared__ float  twgt[TT];
    __shared__ size_t toff[TT];

    const int tid = threadIdx.x;
    const int e = blockIdx.x / maxblk, blk = blockIdx.x % maxblk;
    const int n = counts[e];
    const int start = blk * TT;
    if (start >= n) return;

    if (tid < TT) {
        int i = start + tid;
        int t = (i < n) ? li[(size_t)e * cap + i] : -1;
        tok[tid]  = t;
        twgt[tid] = (i < n) ? lwt[(size_t)e * cap + i] : 0.f;
        toff[tid] = (t >= 0) ? (DIMD == HD_ ? local_off(t) : (size_t)t * D_) : 0;
    }
    __syncthreads();
    for (int i = tid; i < TT * DIMD; i += 256) {
        int tt = i / DIMD, d = i % DIMD;
        xs[tt][d] = (tok[tt] >= 0) ? X[toff[tt] + d] : 0.f;
    }
    __syncthreads();

    float accB0[TT] = {}, accB1[TT] = {};   // DIMD==512 path
    float accBl[TT] = {};                   // DIMD==128 path

    for (int hc = 0; hc < HID_; hc += HC) {
        // ---- Phase A: h1 chunk. Thread owns h = hc + tid*2 + {0,1}.
        {
            float a0[TT] = {}, a1[TT] = {};
            const float* w1p = w1 + (size_t)e * DIMD * HID_ + hc + tid * 2;
            #pragma unroll 4
            for (int d = 0; d < DIMD; d++) {
                float2 wv = *reinterpret_cast<const float2*>(w1p + (size_t)d * HID_);
                #pragma unroll
                for (int tt = 0; tt < TT; tt++) {
                    float xv = xs[tt][d];
                    a0[tt] = fmaf(xv, wv.x, a0[tt]);
                    a1[tt] = fmaf(xv, wv.y, a1[tt]);
                }
            }
            float bb0 = b1[(size_t)e * HID_ + hc + tid * 2];
            float bb1 = b1[(size_t)e * HID_ + hc + tid * 2 + 1];
            __syncthreads();   // prior chunk's Phase-B reads of hs complete
            #pragma unroll
            for (int tt = 0; tt < TT; tt++) {
                float2 hv;
                hv.x = fmaxf(a0[tt] + bb0, 0.f);
                hv.y = fmaxf(a1[tt] + bb1, 0.f);
                *reinterpret_cast<float2*>(&hs[tt][tid * 2]) = hv;
            }
            __syncthreads();
        }
        // ---- Phase B: accumulate out over this h chunk.
        if constexpr (DIMD == D_) {
            const int d0 = tid * 2;
            const float* w2p = w2 + (size_t)e * HID_ * D_ + d0;
            #pragma unroll 4
            for (int h = 0; h < HC; h++) {
                float2 wv = *reinterpret_cast<const float2*>(w2p + (size_t)(hc + h) * D_);
                #pragma unroll
                for (int tt = 0; tt < TT; tt++) {
                    float hv = hs[tt][h];
                    accB0[tt] = fmaf(hv, wv.x, accB0[tt]);
                    accB1[tt] = fmaf(hv, wv.y, accB1[tt]);
                }
            }
        } else {
            const int d = tid & 127, half = tid >> 7;
            const float* w2p = w2 + (size_t)e * HID_ * HD_ + d;
            const int hb = half * (HC / 2);
            #pragma unroll 4
            for (int h = hb; h < hb + HC / 2; h++) {
                float wv = w2p[(size_t)(hc + h) * HD_];
                #pragma unroll
                for (int tt = 0; tt < TT; tt++)
                    accBl[tt] = fmaf(hs[tt][h], wv, accBl[tt]);
            }
        }
    }

    // ---- Scatter
    if constexpr (DIMD == D_) {
        const int d0 = tid * 2;
        float bb0 = b2[(size_t)e * D_ + d0];
        float bb1 = b2[(size_t)e * D_ + d0 + 1];
        #pragma unroll
        for (int tt = 0; tt < TT; tt++) {
            if (tok[tt] >= 0) {
                float w = twgt[tt];
                atomicAdd(&OUT[toff[tt] + d0],     w * (accB0[tt] + bb0));
                atomicAdd(&OUT[toff[tt] + d0 + 1], w * (accB1[tt] + bb1));
            }
        }
    } else {
        __shared__ float ps[256][TT];
        #pragma unroll
        for (int tt = 0; tt < TT; tt++) ps[tid][tt] = accBl[tt];
        __syncthreads();
        if (tid < 128) {
            float bb = b2[(size_t)e * HD_ + tid];
            #pragma unroll
            for (int tt = 0; tt < TT; tt++) {
                if (tok[tt] >= 0) {
                    float tot = ps[tid][tt] + ps[tid + 128][tt];
                    atomicAdd(&OUT[toff[tt] + tid], twgt[tt] * (tot + bb));
                }
            }
        }
    }
}

// ---------------------------------------------------------------------------
// Attention: one 256-thread block per (q-row, b, h). Mask is all-True.
// ---------------------------------------------------------------------------
__global__ __launch_bounds__(256) void attn_k(
    const float* __restrict__ Q, const float* __restrict__ Kb,
    const float* __restrict__ V, float* __restrict__ AO)
{
    __shared__ float qs[128];
    __shared__ float sc[1024];
    __shared__ float red[4];
    __shared__ float po[256];
    const int tid = threadIdx.x;
    const int q = blockIdx.x, bh = blockIdx.y;
    const int b = bh >> 2, h = bh & 3;
    const size_t base = (size_t)b * S_ * D_ + (size_t)h * HD_;

    if (tid < 128) qs[tid] = Q[base + (size_t)q * D_ + tid] * 0.0883883476483184405f; // 1/sqrt(128)
    __syncthreads();

    for (int k = tid; k < S_; k += 256) {
        const float* kr = Kb + base + (size_t)k * D_;
        float s = 0.f;
        #pragma unroll
        for (int d = 0; d < 128; d += 4) {
            float4 kv = *reinterpret_cast<const float4*>(kr + d);
            s = fmaf(qs[d], kv.x, s); s = fmaf(qs[d + 1], kv.y, s);
            s = fmaf(qs[d + 2], kv.z, s); s = fmaf(qs[d + 3], kv.w, s);
        }
        sc[k] = s;
    }
    __syncthreads();

    float m = -1e30f;
    for (int k = tid; k < S_; k += 256) m = fmaxf(m, sc[k]);
    #pragma unroll
    for (int off = 32; off; off >>= 1) m = fmaxf(m, __shfl_xor(m, off));
    if ((tid & 63) == 0) red[tid >> 6] = m;
    __syncthreads();
    m = fmaxf(fmaxf(red[0], red[1]), fmaxf(red[2], red[3]));
    __syncthreads();  // done reading red before reuse

    float sum = 0.f;
    for (int k = tid; k < S_; k += 256) { float e2 = __expf(sc[k] - m); sc[k] = e2; sum += e2; }
    #pragma unroll
    for (int off = 32; off; off >>= 1) sum += __shfl_xor(sum, off);
    if ((tid & 63) == 0) red[tid >> 6] = sum;
    __syncthreads();
    const float inv = 1.f / (red[0] + red[1] + red[2] + red[3]);

    const int d = tid & 127, half = tid >> 7;
    float o = 0.f;
    const float* vb = V + base + d;
    for (int k = half * 512; k < half * 512 + 512; k++)
        o = fmaf(sc[k], vb[(size_t)k * D_], o);
    po[tid] = o;
    __syncthreads();
    if (tid < 128)
        AO[base + (size_t)q * D_ + tid] = (po[tid] + po[tid + 128]) * inv;
}

// fp32 -> fp32 output copy (vectorized)
__global__ __launch_bounds__(256) void copy_out_k(
    const float* __restrict__ X, float* __restrict__ Y, int n)
{
    int base = (blockIdx.x * 256 + threadIdx.x) * 4;
    if (base < n)
        *reinterpret_cast<float4*>(Y + base) = *reinterpret_cast<const float4*>(X + base);
}

// ---------------------------------------------------------------------------
extern "C" void kernel_launch(void* const* d_in, const int* in_sizes, int n_in,
                              void* d_out, int out_size, void* d_ws, size_t ws_size,
                              hipStream_t stream)
{
    (void)in_sizes; (void)n_in; (void)out_size; (void)ws_size;
    const float* x        = (const float*)d_in[0];
    const float* pre_w    = (const float*)d_in[1];
    const float* pre_b    = (const float*)d_in[2];
    const float* l_gate_w = (const float*)d_in[3];
    const float* l_gate_b = (const float*)d_in[4];
    const float* l_w1     = (const float*)d_in[5];
    const float* l_b1     = (const float*)d_in[6];
    const float* l_w2     = (const float*)d_in[7];
    const float* l_b2     = (const float*)d_in[8];
    const float* align_w  = (const float*)d_in[9];
    const float* align_b  = (const float*)d_in[10];
    const float* ln1_w    = (const float*)d_in[11];
    const float* ln1_b    = (const float*)d_in[12];
    const float* wq       = (const float*)d_in[13];
    const float* bq       = (const float*)d_in[14];
    const float* wk       = (const float*)d_in[15];
    const float* bk       = (const float*)d_in[16];
    const float* wv       = (const float*)d_in[17];
    const float* bv       = (const float*)d_in[18];
    const float* wo       = (const float*)d_in[19];
    const float* bo       = (const float*)d_in[20];
    const float* ln2_w    = (const float*)d_in[21];
    const float* ln2_b    = (const float*)d_in[22];
    const float* g_gate_w = (const float*)d_in[23];
    const float* g_gate_b = (const float*)d_in[24];
    const float* g_w1     = (const float*)d_in[25];
    const float* g_b1     = (const float*)d_in[26];
    const float* g_w2     = (const float*)d_in[27];
    const float* g_b2     = (const float*)d_in[28];
    // d_in[29] = mask: all-True, no-op in reference semantics -> ignored.

    char* ws = (char*)d_ws;
    const size_t MB4 = (size_t)NTOK * D_ * sizeof(float);  // 4 MiB
    float* W0 = (float*)(ws + 0 * MB4);
    float* W1 = (float*)(ws + 1 * MB4);
    float* W2 = (float*)(ws + 2 * MB4);
    float* W3 = (float*)(ws + 3 * MB4);
    float* W4 = (float*)(ws + 4 * MB4);
    char*  p  = ws + 5 * MB4;
    int*   lcnt = (int*)p;            p += 8 * sizeof(int);
    int*   gcnt = (int*)p;            p += 8 * sizeof(int);
    int*   lli  = (int*)p;            p += (size_t)E_ * NSUB * sizeof(int);
    float* llw  = (float*)p;          p += (size_t)E_ * NSUB * sizeof(float);
    int*   gli  = (int*)p;            p += (size_t)E_ * NTOK * sizeof(int);
    float* glw  = (float*)p;

    hipMemsetAsync(lcnt, 0, 16 * sizeof(int), stream);  // lcnt + gcnt contiguous

    const dim3 gg(D_ / 64, NTOK / 64);  // (8, 32)

    // 1. xp = x @ pre_w + pre_b                            -> W0
    gemm_bias_k<false><<<gg, 256, 0, stream>>>(x, pre_w, pre_b, nullptr, W0, NTOK, D_, D_);
    // 2. local gating (per sub-token)
    gate_k<true><<<NSUB, 64, 0, stream>>>(W0, l_gate_w, l_gate_b, lcnt, lli, llw, NSUB);
    // 3. xmo = xp (expert outputs accumulate on top)       -> W1
    hipMemcpyAsync(W1, W0, MB4, hipMemcpyDeviceToDevice, stream);
    // 4. local expert FFN (grouped, atomic accumulate)
    ffn_k<HD_><<<E_ * (NSUB / TT), 256, 0, stream>>>(W0, l_w1, l_b1, l_w2, l_b2,
                                                     lcnt, lli, llw, W1, NSUB / TT, NSUB);
    // 5. xl = xmo @ align_w + align_b                      -> W2
    gemm_bias_k<false><<<gg, 256, 0, stream>>>(W1, align_w, align_b, nullptr, W2, NTOK, D_, D_);
    // 6. xn1 = LN(xl)                                      -> W0
    ln_k<<<NTOK, 256, 0, stream>>>(W2, ln1_w, ln1_b, W0);
    // 7. Q,K,V                                             -> W1,W2,W3
    gemm_bias_k<false><<<gg, 256, 0, stream>>>(W0, wq, bq, nullptr, W1, NTOK, D_, D_);
    gemm_bias_k<false><<<gg, 256, 0, stream>>>(W0, wk, bk, nullptr, W2, NTOK, D_, D_);
    gemm_bias_k<false><<<gg, 256, 0, stream>>>(W0, wv, bv, nullptr, W3, NTOK, D_, D_);
    // 8. attention                                         -> W4
    attn_k<<<dim3(S_, B_ * AH_), 256, 0, stream>>>(W1, W2, W3, W4);
    // 9. x1 = x + AO @ wo + bo                             -> W1
    gemm_bias_k<true><<<gg, 256, 0, stream>>>(W4, wo, bo, x, W1, NTOK, D_, D_);
    // 10. xn2 = LN(x1)                                     -> W2
    ln_k<<<NTOK, 256, 0, stream>>>(W1, ln2_w, ln2_b, W2);
    // 11. global gating
    gate_k<false><<<NTOK, 64, 0, stream>>>(W2, g_gate_w, g_gate_b, gcnt, gli, glw, NTOK);
    // 12. global expert FFN -> accumulate directly into x1 (W1)
    ffn_k<D_><<<E_ * (NTOK / TT), 256, 0, stream>>>(W2, g_w1, g_b1, g_w2, g_b2,
                                                    gcnt, gli, glw, W1, NTOK / TT, NTOK);
    // 13. out = W1 (fp32)
    copy_out_k<<<(NTOK * D_) / (256 * 4), 256, 0, stream>>>(W1, (float*)d_out, NTOK * D_);
}

// Round 4
// 1805.459 us; speedup vs baseline: 1.7793x; 1.7793x over previous
//
#include <hip/hip_runtime.h>

typedef unsigned short ushort_t;

// Problem constants
constexpr int B_    = 2;
constexpr int S_    = 1024;
constexpr int D_    = 512;
constexpr int E_    = 8;
constexpr int HMOE_ = 4;
constexpr int HD_   = 128;
constexpr int HID_  = 2048;
constexpr int AH_   = 4;
constexpr int NTOK  = B_ * S_;          // 2048 tokens
constexpr int NSUB  = B_ * HMOE_ * S_;  // 8192 sub-tokens
constexpr int TT    = 8;                // tokens per FFN workgroup

#define DEVINL __device__ __forceinline__

// ---------------------------------------------------------------------------
// GEMM: C[M,N] = A[M,K] @ W[K,N] + bias  (+ optional fp32 residual R)
// All fp32. 64x64 tile, BK=16, 256 threads, 4x4 per thread.
// ---------------------------------------------------------------------------
template <bool ADD_R>
__global__ __launch_bounds__(256) void gemm_bias_k(
    const float* __restrict__ A, const float* __restrict__ W,
    const float* __restrict__ bias, const float* __restrict__ R,
    float* __restrict__ C, int M, int N, int Kd)
{
    __shared__ float As[16][68];
    __shared__ float Bs[16][68];
    const int tid = threadIdx.x;
    const int tx = tid & 15, ty = tid >> 4;
    const int m0 = blockIdx.y * 64, n0 = blockIdx.x * 64;
    float acc[4][4] = {};
    for (int k0 = 0; k0 < Kd; k0 += 16) {
        #pragma unroll
        for (int j = 0; j < 4; j++) {
            int i = tid + 256 * j;
            int mm = i >> 4, kk = i & 15;
            As[kk][mm] = A[(size_t)(m0 + mm) * Kd + k0 + kk];
        }
        {
            int row = tid >> 4, col = (tid & 15) * 4;
            float4 bv = *reinterpret_cast<const float4*>(W + (size_t)(k0 + row) * N + n0 + col);
            *reinterpret_cast<float4*>(&Bs[row][col]) = bv;
        }
        __syncthreads();
        #pragma unroll
        for (int kk = 0; kk < 16; kk++) {
            float4 a = *reinterpret_cast<const float4*>(&As[kk][ty * 4]);
            float4 b = *reinterpret_cast<const float4*>(&Bs[kk][tx * 4]);
            float av[4] = {a.x, a.y, a.z, a.w};
            float bv[4] = {b.x, b.y, b.z, b.w};
            #pragma unroll
            for (int i = 0; i < 4; i++)
                #pragma unroll
                for (int j = 0; j < 4; j++)
                    acc[i][j] = fmaf(av[i], bv[j], acc[i][j]);
        }
        __syncthreads();
    }
    #pragma unroll
    for (int i = 0; i < 4; i++) {
        int m = m0 + ty * 4 + i;
        #pragma unroll
        for (int j = 0; j < 4; j++) {
            int n = n0 + tx * 4 + j;
            float v = acc[i][j] + bias[n];
            if (ADD_R) v += R[(size_t)m * N + n];
            C[(size_t)m * N + n] = v;
        }
    }
}

// ---------------------------------------------------------------------------
// LayerNorm over D=512, one 256-thread block per row. All fp32.
// ---------------------------------------------------------------------------
__global__ __launch_bounds__(256) void ln_k(
    const float* __restrict__ X, const float* __restrict__ w,
    const float* __restrict__ b, float* __restrict__ Y)
{
    __shared__ float red[8];
    const int row = blockIdx.x, tid = threadIdx.x;
    const float* x = X + (size_t)row * D_;
    float v0 = x[tid], v1 = x[tid + 256];
    float s = v0 + v1, ss = v0 * v0 + v1 * v1;
    #pragma unroll
    for (int off = 32; off; off >>= 1) {
        s  += __shfl_xor(s, off);
        ss += __shfl_xor(ss, off);
    }
    if ((tid & 63) == 0) { red[tid >> 6] = s; red[(tid >> 6) + 4] = ss; }
    __syncthreads();
    float mu  = (red[0] + red[1] + red[2] + red[3]) * (1.f / D_);
    float var = (red[4] + red[5] + red[6] + red[7]) * (1.f / D_) - mu * mu;
    float rs = rsqrtf(var + 1e-12f);
    Y[(size_t)row * D_ + tid]       = (v0 - mu) * rs * w[tid]       + b[tid];
    Y[(size_t)row * D_ + tid + 256] = (v1 - mu) * rs * w[tid + 256] + b[tid + 256];
}

// sub-token t = ((b*HMOE + h)*S + s)  ->  flat offset into [b,s,512] at col h*128
DEVINL size_t local_off(int t) {
    int bq = t >> 12, r = t & 4095, h = r >> 10, sI = r & 1023;
    return ((size_t)(bq * S_ + sI)) * D_ + (size_t)h * HD_;
}

// ---------------------------------------------------------------------------
// Gating: one wave per token. softmax over 8 experts, top-2 (lowest-index
// tie-break = lax.top_k), re-softmax of top-2 probs, atomic list append.
// ---------------------------------------------------------------------------
template <bool LOCAL>
__global__ __launch_bounds__(64) void gate_k(
    const float* __restrict__ X, const float* __restrict__ gw,
    const float* __restrict__ gb, int* __restrict__ counts,
    int* __restrict__ li, float* __restrict__ lwt, int cap)
{
    constexpr int DIMD = LOCAL ? HD_ : D_;
    constexpr int PL = DIMD / 64;
    const int t = blockIdx.x, lane = threadIdx.x;
    const float* x = X + (LOCAL ? local_off(t) : (size_t)t * D_);
    float xr[PL];
    #pragma unroll
    for (int i = 0; i < PL; i++) xr[i] = x[lane + 64 * i];
    float sc[8];
    #pragma unroll
    for (int e = 0; e < 8; e++) {
        float a = 0.f;
        #pragma unroll
        for (int i = 0; i < PL; i++)
            a = fmaf(xr[i], gw[(size_t)(lane + 64 * i) * E_ + e], a);
        #pragma unroll
        for (int o2 = 32; o2; o2 >>= 1) a += __shfl_xor(a, o2);
        sc[e] = a;
    }
    if (lane == 0) {
        float mx = -1e30f;
        #pragma unroll
        for (int e = 0; e < 8; e++) { sc[e] += gb[e]; mx = fmaxf(mx, sc[e]); }
        float p[8], psum = 0.f;
        #pragma unroll
        for (int e = 0; e < 8; e++) { p[e] = expf(sc[e] - mx); psum += p[e]; }
        float inv = 1.f / psum;
        #pragma unroll
        for (int e = 0; e < 8; e++) p[e] *= inv;
        int i0 = 0;
        for (int e = 1; e < 8; e++) if (p[e] > p[i0]) i0 = e;
        int i1 = (i0 == 0) ? 1 : 0;
        for (int e = 0; e < 8; e++) if (e != i0 && p[e] > p[i1]) i1 = e;
        float e0 = expf(p[i0]), e1 = expf(p[i1]);
        float wnorm = 1.f / (e0 + e1);
        int pos0 = atomicAdd(&counts[i0], 1);
        li[(size_t)i0 * cap + pos0] = t; lwt[(size_t)i0 * cap + pos0] = e0 * wnorm;
        int pos1 = atomicAdd(&counts[i1], 1);
        li[(size_t)i1 * cap + pos1] = t; lwt[(size_t)i1 * cap + pos1] = e1 * wnorm;
    }
}

// ---------------------------------------------------------------------------
// Grouped expert FFN (unchanged from R3).
// ---------------------------------------------------------------------------
template <int DIMD>
__global__ __launch_bounds__(256) void ffn_k(
    const float* __restrict__ X,
    const float* __restrict__ w1, const float* __restrict__ b1,
    const float* __restrict__ w2, const float* __restrict__ b2,
    const int* __restrict__ counts, const int* __restrict__ li,
    const float* __restrict__ lwt, float* __restrict__ OUT,
    int maxblk, int cap)
{
    constexpr int HC = 512;  // h-chunk
    __shared__ float xs[TT][DIMD];
    __shared__ float hs[TT][HC];
    __shared__ int    tok[TT];
    __shared__ float  twgt[TT];
    __shared__ size_t toff[TT];

    const int tid = threadIdx.x;
    const int e = blockIdx.x / maxblk, blk = blockIdx.x % maxblk;
    const int n = counts[e];
    const int start = blk * TT;
    if (start >= n) return;

    if (tid < TT) {
        int i = start + tid;
        int t = (i < n) ? li[(size_t)e * cap + i] : -1;
        tok[tid]  = t;
        twgt[tid] = (i < n) ? lwt[(size_t)e * cap + i] : 0.f;
        toff[tid] = (t >= 0) ? (DIMD == HD_ ? local_off(t) : (size_t)t * D_) : 0;
    }
    __syncthreads();
    for (int i = tid; i < TT * DIMD; i += 256) {
        int tt = i / DIMD, d = i % DIMD;
        xs[tt][d] = (tok[tt] >= 0) ? X[toff[tt] + d] : 0.f;
    }
    __syncthreads();

    float accB0[TT] = {}, accB1[TT] = {};   // DIMD==512 path
    float accBl[TT] = {};                   // DIMD==128 path

    for (int hc = 0; hc < HID_; hc += HC) {
        {
            float a0[TT] = {}, a1[TT] = {};
            const float* w1p = w1 + (size_t)e * DIMD * HID_ + hc + tid * 2;
            #pragma unroll 4
            for (int d = 0; d < DIMD; d++) {
                float2 wv = *reinterpret_cast<const float2*>(w1p + (size_t)d * HID_);
                #pragma unroll
                for (int tt = 0; tt < TT; tt++) {
                    float xv = xs[tt][d];
                    a0[tt] = fmaf(xv, wv.x, a0[tt]);
                    a1[tt] = fmaf(xv, wv.y, a1[tt]);
                }
            }
            float bb0 = b1[(size_t)e * HID_ + hc + tid * 2];
            float bb1 = b1[(size_t)e * HID_ + hc + tid * 2 + 1];
            __syncthreads();
            #pragma unroll
            for (int tt = 0; tt < TT; tt++) {
                float2 hv;
                hv.x = fmaxf(a0[tt] + bb0, 0.f);
                hv.y = fmaxf(a1[tt] + bb1, 0.f);
                *reinterpret_cast<float2*>(&hs[tt][tid * 2]) = hv;
            }
            __syncthreads();
        }
        if constexpr (DIMD == D_) {
            const int d0 = tid * 2;
            const float* w2p = w2 + (size_t)e * HID_ * D_ + d0;
            #pragma unroll 4
            for (int h = 0; h < HC; h++) {
                float2 wv = *reinterpret_cast<const float2*>(w2p + (size_t)(hc + h) * D_);
                #pragma unroll
                for (int tt = 0; tt < TT; tt++) {
                    float hv = hs[tt][h];
                    accB0[tt] = fmaf(hv, wv.x, accB0[tt]);
                    accB1[tt] = fmaf(hv, wv.y, accB1[tt]);
                }
            }
        } else {
            const int d = tid & 127, half = tid >> 7;
            const float* w2p = w2 + (size_t)e * HID_ * HD_ + d;
            const int hb = half * (HC / 2);
            #pragma unroll 4
            for (int h = hb; h < hb + HC / 2; h++) {
                float wv = w2p[(size_t)(hc + h) * HD_];
                #pragma unroll
                for (int tt = 0; tt < TT; tt++)
                    accBl[tt] = fmaf(hs[tt][h], wv, accBl[tt]);
            }
        }
    }

    if constexpr (DIMD == D_) {
        const int d0 = tid * 2;
        float bb0 = b2[(size_t)e * D_ + d0];
        float bb1 = b2[(size_t)e * D_ + d0 + 1];
        #pragma unroll
        for (int tt = 0; tt < TT; tt++) {
            if (tok[tt] >= 0) {
                float w = twgt[tt];
                atomicAdd(&OUT[toff[tt] + d0],     w * (accB0[tt] + bb0));
                atomicAdd(&OUT[toff[tt] + d0 + 1], w * (accB1[tt] + bb1));
            }
        }
    } else {
        __shared__ float ps[256][TT];
        #pragma unroll
        for (int tt = 0; tt < TT; tt++) ps[tid][tt] = accBl[tt];
        __syncthreads();
        if (tid < 128) {
            float bb = b2[(size_t)e * HD_ + tid];
            #pragma unroll
            for (int tt = 0; tt < TT; tt++) {
                if (tok[tt] >= 0) {
                    float tot = ps[tid][tt] + ps[tid + 128][tt];
                    atomicAdd(&OUT[toff[tt] + tid], twgt[tt] * (tot + bb));
                }
            }
        }
    }
}

// ---------------------------------------------------------------------------
// Flash-style attention. Grid (S/QT=32, B*AH=8), 256 threads.
// Q-tile (32 rows) and K-chunks (64 rows) staged TRANSPOSED in LDS so the
// score phase is a register-tiled GEMM over d. Online softmax (m,l,alpha in
// LDS). PV reads V from global (coalesced, L1-resident per chunk).
// LDS: qsT 18.4K + kst 34.8K + psT 9.2K + stats 0.4K = 62.8 KB (<64 KB).
// ---------------------------------------------------------------------------
constexpr int QT = 32;
constexpr int KC = 64;

__global__ __launch_bounds__(256) void fattn_k(
    const float* __restrict__ Q, const float* __restrict__ Kb,
    const float* __restrict__ V, float* __restrict__ AO)
{
    __shared__ float qsT[128][QT + 4];   // [d][q], pre-scaled
    __shared__ float kst[128][KC + 4];   // [d][k]
    __shared__ float psT[KC][QT + 4];    // [k][q]: scores -> p
    __shared__ float mrow[QT], lrow[QT], arow[QT];

    const int tid = threadIdx.x;
    const int q0 = blockIdx.x * QT;
    const int bh = blockIdx.y, b = bh >> 2, h = bh & 3;
    const size_t base = (size_t)b * S_ * D_ + (size_t)h * HD_;
    const float scale = 0.08838834764831844f;  // 1/sqrt(128)

    // stage Q tile transposed + scaled
    for (int i = tid * 4; i < QT * 128; i += 1024) {
        int r = i >> 7, c = i & 127;
        float4 v = *reinterpret_cast<const float4*>(Q + base + (size_t)(q0 + r) * D_ + c);
        qsT[c + 0][r] = v.x * scale; qsT[c + 1][r] = v.y * scale;
        qsT[c + 2][r] = v.z * scale; qsT[c + 3][r] = v.w * scale;
    }
    if (tid < QT) { mrow[tid] = -1e30f; lrow[tid] = 0.f; }

    const int sx = tid & 15, sy = tid >> 4;   // score map: 2q x 4k
    const int px = tid & 31, py = tid >> 5;   // PV map:    4q x 4d
    float o[4][4] = {};
    __syncthreads();

    for (int kc = 0; kc < S_; kc += KC) {
        // stage K chunk transposed
        for (int i = tid * 4; i < KC * 128; i += 1024) {
            int r = i >> 7, c = i & 127;
            float4 v = *reinterpret_cast<const float4*>(Kb + base + (size_t)(kc + r) * D_ + c);
            kst[c + 0][r] = v.x; kst[c + 1][r] = v.y;
            kst[c + 2][r] = v.z; kst[c + 3][r] = v.w;
        }
        __syncthreads();

        // scores: thread tile 2q x 4k over d=128
        {
            float s[2][4] = {};
            #pragma unroll 8
            for (int d = 0; d < 128; d++) {
                float a0 = qsT[d][sy * 2];
                float a1 = qsT[d][sy * 2 + 1];
                float4 kb4 = *reinterpret_cast<const float4*>(&kst[d][sx * 4]);
                s[0][0] = fmaf(a0, kb4.x, s[0][0]); s[0][1] = fmaf(a0, kb4.y, s[0][1]);
                s[0][2] = fmaf(a0, kb4.z, s[0][2]); s[0][3] = fmaf(a0, kb4.w, s[0][3]);
                s[1][0] = fmaf(a1, kb4.x, s[1][0]); s[1][1] = fmaf(a1, kb4.y, s[1][1]);
                s[1][2] = fmaf(a1, kb4.z, s[1][2]); s[1][3] = fmaf(a1, kb4.w, s[1][3]);
            }
            #pragma unroll
            for (int j = 0; j < 4; j++) {
                psT[sx * 4 + j][sy * 2]     = s[0][j];
                psT[sx * 4 + j][sy * 2 + 1] = s[1][j];
            }
        }
        __syncthreads();

        // online-softmax stats: row r handled by 8 contiguous lanes, 8 cols each
        {
            int r = tid >> 3, c0 = (tid & 7) * 8;
            float vals[8];
            float mx = -1e30f;
            #pragma unroll
            for (int j = 0; j < 8; j++) { vals[j] = psT[c0 + j][r]; mx = fmaxf(mx, vals[j]); }
            mx = fmaxf(mx, __shfl_xor(mx, 1));
            mx = fmaxf(mx, __shfl_xor(mx, 2));
            mx = fmaxf(mx, __shfl_xor(mx, 4));
            float mold = mrow[r];
            float mnew = fmaxf(mold, mx);
            float alpha = __expf(mold - mnew);
            float sum = 0.f;
            #pragma unroll
            for (int j = 0; j < 8; j++) {
                float pexp = __expf(vals[j] - mnew);
                psT[c0 + j][r] = pexp;
                sum += pexp;
            }
            sum += __shfl_xor(sum, 1);
            sum += __shfl_xor(sum, 2);
            sum += __shfl_xor(sum, 4);
            if ((tid & 7) == 0) { mrow[r] = mnew; lrow[r] = lrow[r] * alpha + sum; arow[r] = alpha; }
        }
        __syncthreads();

        // PV: o[4q][4d] += P^T-chunk @ V-chunk (V from global)
        {
            #pragma unroll
            for (int i2 = 0; i2 < 4; i2++) {
                float al = arow[py * 4 + i2];
                #pragma unroll
                for (int j = 0; j < 4; j++) o[i2][j] *= al;
            }
            #pragma unroll 4
            for (int k = 0; k < KC; k++) {
                float4 pv = *reinterpret_cast<const float4*>(&psT[k][py * 4]);
                float4 vv = *reinterpret_cast<const float4*>(V + base + (size_t)(kc + k) * D_ + px * 4);
                float pa[4] = {pv.x, pv.y, pv.z, pv.w};
                #pragma unroll
                for (int i2 = 0; i2 < 4; i2++) {
                    o[i2][0] = fmaf(pa[i2], vv.x, o[i2][0]);
                    o[i2][1] = fmaf(pa[i2], vv.y, o[i2][1]);
                    o[i2][2] = fmaf(pa[i2], vv.z, o[i2][2]);
                    o[i2][3] = fmaf(pa[i2], vv.w, o[i2][3]);
                }
            }
        }
        __syncthreads();  // protect psT/arow from next chunk's overwrite
    }

    // epilogue: divide by l, write out
    #pragma unroll
    for (int i2 = 0; i2 < 4; i2++) {
        float inv = 1.f / lrow[py * 4 + i2];
        float4 ov;
        ov.x = o[i2][0] * inv; ov.y = o[i2][1] * inv;
        ov.z = o[i2][2] * inv; ov.w = o[i2][3] * inv;
        *reinterpret_cast<float4*>(AO + base + (size_t)(q0 + py * 4 + i2) * D_ + px * 4) = ov;
    }
}

// fp32 -> fp32 output copy (vectorized)
__global__ __launch_bounds__(256) void copy_out_k(
    const float* __restrict__ X, float* __restrict__ Y, int n)
{
    int base = (blockIdx.x * 256 + threadIdx.x) * 4;
    if (base < n)
        *reinterpret_cast<float4*>(Y + base) = *reinterpret_cast<const float4*>(X + base);
}

// ---------------------------------------------------------------------------
extern "C" void kernel_launch(void* const* d_in, const int* in_sizes, int n_in,
                              void* d_out, int out_size, void* d_ws, size_t ws_size,
                              hipStream_t stream)
{
    (void)in_sizes; (void)n_in; (void)out_size; (void)ws_size;
    const float* x        = (const float*)d_in[0];
    const float* pre_w    = (const float*)d_in[1];
    const float* pre_b    = (const float*)d_in[2];
    const float* l_gate_w = (const float*)d_in[3];
    const float* l_gate_b = (const float*)d_in[4];
    const float* l_w1     = (const float*)d_in[5];
    const float* l_b1     = (const float*)d_in[6];
    const float* l_w2     = (const float*)d_in[7];
    const float* l_b2     = (const float*)d_in[8];
    const float* align_w  = (const float*)d_in[9];
    const float* align_b  = (const float*)d_in[10];
    const float* ln1_w    = (const float*)d_in[11];
    const float* ln1_b    = (const float*)d_in[12];
    const float* wq       = (const float*)d_in[13];
    const float* bq       = (const float*)d_in[14];
    const float* wk       = (const float*)d_in[15];
    const float* bk       = (const float*)d_in[16];
    const float* wv       = (const float*)d_in[17];
    const float* bv       = (const float*)d_in[18];
    const float* wo       = (const float*)d_in[19];
    const float* bo       = (const float*)d_in[20];
    const float* ln2_w    = (const float*)d_in[21];
    const float* ln2_b    = (const float*)d_in[22];
    const float* g_gate_w = (const float*)d_in[23];
    const float* g_gate_b = (const float*)d_in[24];
    const float* g_w1     = (const float*)d_in[25];
    const float* g_b1     = (const float*)d_in[26];
    const float* g_w2     = (const float*)d_in[27];
    const float* g_b2     = (const float*)d_in[28];
    // d_in[29] = mask: all-True, no-op in reference semantics -> ignored.

    char* ws = (char*)d_ws;
    const size_t MB4 = (size_t)NTOK * D_ * sizeof(float);  // 4 MiB
    float* W0 = (float*)(ws + 0 * MB4);
    float* W1 = (float*)(ws + 1 * MB4);
    float* W2 = (float*)(ws + 2 * MB4);
    float* W3 = (float*)(ws + 3 * MB4);
    float* W4 = (float*)(ws + 4 * MB4);
    char*  p  = ws + 5 * MB4;
    int*   lcnt = (int*)p;            p += 8 * sizeof(int);
    int*   gcnt = (int*)p;            p += 8 * sizeof(int);
    int*   lli  = (int*)p;            p += (size_t)E_ * NSUB * sizeof(int);
    float* llw  = (float*)p;          p += (size_t)E_ * NSUB * sizeof(float);
    int*   gli  = (int*)p;            p += (size_t)E_ * NTOK * sizeof(int);
    float* glw  = (float*)p;

    hipMemsetAsync(lcnt, 0, 16 * sizeof(int), stream);  // lcnt + gcnt contiguous

    const dim3 gg(D_ / 64, NTOK / 64);  // (8, 32)

    // 1. xp = x @ pre_w + pre_b                            -> W0
    gemm_bias_k<false><<<gg, 256, 0, stream>>>(x, pre_w, pre_b, nullptr, W0, NTOK, D_, D_);
    // 2. local gating (per sub-token)
    gate_k<true><<<NSUB, 64, 0, stream>>>(W0, l_gate_w, l_gate_b, lcnt, lli, llw, NSUB);
    // 3. xmo = xp (expert outputs accumulate on top)       -> W1
    hipMemcpyAsync(W1, W0, MB4, hipMemcpyDeviceToDevice, stream);
    // 4. local expert FFN (grouped, atomic accumulate)
    ffn_k<HD_><<<E_ * (NSUB / TT), 256, 0, stream>>>(W0, l_w1, l_b1, l_w2, l_b2,
                                                     lcnt, lli, llw, W1, NSUB / TT, NSUB);
    // 5. xl = xmo @ align_w + align_b                      -> W2
    gemm_bias_k<false><<<gg, 256, 0, stream>>>(W1, align_w, align_b, nullptr, W2, NTOK, D_, D_);
    // 6. xn1 = LN(xl)                                      -> W0
    ln_k<<<NTOK, 256, 0, stream>>>(W2, ln1_w, ln1_b, W0);
    // 7. Q,K,V                                             -> W1,W2,W3
    gemm_bias_k<false><<<gg, 256, 0, stream>>>(W0, wq, bq, nullptr, W1, NTOK, D_, D_);
    gemm_bias_k<false><<<gg, 256, 0, stream>>>(W0, wk, bk, nullptr, W2, NTOK, D_, D_);
    gemm_bias_k<false><<<gg, 256, 0, stream>>>(W0, wv, bv, nullptr, W3, NTOK, D_, D_);
    // 8. attention (flash-style)                           -> W4
    fattn_k<<<dim3(S_ / QT, B_ * AH_), 256, 0, stream>>>(W1, W2, W3, W4);
    // 9. x1 = x + AO @ wo + bo                             -> W1
    gemm_bias_k<true><<<gg, 256, 0, stream>>>(W4, wo, bo, x, W1, NTOK, D_, D_);
    // 10. xn2 = LN(x1)                                     -> W2
    ln_k<<<NTOK, 256, 0, stream>>>(W1, ln2_w, ln2_b, W2);
    // 11. global gating
    gate_k<false><<<NTOK, 64, 0, stream>>>(W2, g_gate_w, g_gate_b, gcnt, gli, glw, NTOK);
    // 12. global expert FFN -> accumulate directly into x1 (W1)
    ffn_k<D_><<<E_ * (NTOK / TT), 256, 0, stream>>>(W2, g_w1, g_b1, g_w2, g_b2,
                                                    gcnt, gli, glw, W1, NTOK / TT, NTOK);
    // 13. out = W1 (fp32)
    copy_out_k<<<(NTOK * D_) / (256 * 4), 256, 0, stream>>>(W1, (float*)d_out, NTOK * D_);
}